// Round 5
// baseline (617.744 us; speedup 1.0000x reference)
//
#include <hip/hip_runtime.h>
#include <cstdint>

// ---- types ----
typedef __bf16  bf16;
typedef __bf16  bf16x8 __attribute__((ext_vector_type(8)));
typedef __bf16  bf16x4 __attribute__((ext_vector_type(4)));
typedef float   f32x4  __attribute__((ext_vector_type(4)));
typedef float   f32x16 __attribute__((ext_vector_type(16)));

#define GLOAD_LDS16(g, l) __builtin_amdgcn_global_load_lds( \
    (const __attribute__((address_space(1))) void*)(g),     \
    (__attribute__((address_space(3))) void*)(l), 16, 0, 0)

// dims
#define SEQ   2048
#define HID   2048
#define NH    16
#define NKV   8
#define HD    128
#define NQKV  6144   // 4096 q_all + 1024 k + 1024 v
#define MTOT  4096   // B*SEQ

// ---------------- fused prep: convx + all weight transposes ----------------
__device__ __forceinline__ void transw_body(const float* __restrict__ W, bf16* __restrict__ WT,
                                            int N, int n0, int k0, int t) {
    __shared__ float tile[64][65];
    int tn = t & 63, t4 = t >> 6;
    #pragma unroll
    for (int i = 0; i < 16; ++i) {
        int kk = i * 4 + t4;
        tile[kk][tn] = W[(size_t)(k0 + kk) * N + n0 + tn];
    }
    __syncthreads();
    #pragma unroll
    for (int i = 0; i < 16; ++i) {
        int nn = i * 4 + t4;
        WT[(size_t)(n0 + nn) * HID + k0 + tn] = (bf16)tile[tn][nn];
    }
}

__global__ __launch_bounds__(256) void prep_kernel(const float* __restrict__ x, bf16* __restrict__ xb,
                                                   const float* __restrict__ Wq, const float* __restrict__ Wk,
                                                   const float* __restrict__ Wv, const float* __restrict__ Wo,
                                                   bf16* __restrict__ wqkvT, bf16* __restrict__ woT) {
    int bx = blockIdx.x, t = threadIdx.x;
    if (bx < 8192) {                                   // convx: 4 f32->bf16 per thread
        int i = bx * 256 + t;
        f32x4 v = ((const f32x4*)x)[i];
        bf16x4 o;
        o[0] = (bf16)v[0]; o[1] = (bf16)v[1]; o[2] = (bf16)v[2]; o[3] = (bf16)v[3];
        ((bf16x4*)xb)[i] = o;
    } else if (bx < 8192 + 2048) {                     // Wq: N=4096
        int idx = bx - 8192;
        transw_body(Wq, wqkvT, 4096, (idx & 63) * 64, (idx >> 6) * 64, t);
    } else if (bx < 8192 + 2048 + 512) {               // Wk: N=1024
        int idx = bx - (8192 + 2048);
        transw_body(Wk, wqkvT + (size_t)4096 * HID, 1024, (idx & 15) * 64, (idx >> 4) * 64, t);
    } else if (bx < 8192 + 2048 + 1024) {              // Wv: N=1024
        int idx = bx - (8192 + 2048 + 512);
        transw_body(Wv, wqkvT + (size_t)5120 * HID, 1024, (idx & 15) * 64, (idx >> 4) * 64, t);
    } else {                                           // Wo: N=2048
        int idx = bx - (8192 + 2048 + 1024);
        transw_body(Wo, woT, 2048, (idx & 31) * 64, (idx >> 5) * 64, t);
    }
}

// ---------------- MFMA GEMM: C[M,N] = A[M,K] * Bt[N,K]^T ----------------
// 128x128 tile, BK=32, 4 waves (64x64 quadrants), 32x32x16 MFMA.
// LDS XOR-swizzle: chunk' = chunk ^ ((row>>1)&3) -> conflict-free b128 reads.
template<bool OUT_BF16>
__global__ __launch_bounds__(256) void gemm_bt(const bf16* __restrict__ A, const bf16* __restrict__ Bt,
                                               void* __restrict__ C, int M, int N, int K) {
    __shared__ __align__(16) bf16 As[128 * 32];
    __shared__ __align__(16) bf16 Bs[128 * 32];
    const int tid = threadIdx.x;
    const int wave = tid >> 6, lane = tid & 63;
    const int l31 = lane & 31, half = lane >> 5;
    const int tile_n = blockIdx.x * 128, tile_m = blockIdx.y * 128;
    const int wm = (wave & 1) * 64, wn = (wave >> 1) * 64;
    const int sw = (l31 >> 1) & 3;                      // read-side swizzle
    f32x16 acc[2][2] = {};

    for (int k0 = 0; k0 < K; k0 += 32) {
        #pragma unroll
        for (int j = 0; j < 2; ++j) {
            int c = (j * 4 + wave) * 64 + lane;          // LDS slot 0..511
            int row = c >> 2, kq = c & 3;
            int kqs = kq ^ ((row >> 1) & 3);             // fetch permuted chunk
            GLOAD_LDS16(A  + (size_t)(tile_m + row) * K + k0 + kqs * 8, As + (size_t)(j * 4 + wave) * 512);
            GLOAD_LDS16(Bt + (size_t)(tile_n + row) * K + k0 + kqs * 8, Bs + (size_t)(j * 4 + wave) * 512);
        }
        __syncthreads();
        bf16x8 a[2][2], b[2][2];
        #pragma unroll
        for (int mt = 0; mt < 2; ++mt)
            #pragma unroll
            for (int kh = 0; kh < 2; ++kh) {
                int ch = ((kh * 2 + half) ^ sw) << 3;
                a[mt][kh] = *(const bf16x8*)(As + (size_t)(wm + mt * 32 + l31) * 32 + ch);
                b[mt][kh] = *(const bf16x8*)(Bs + (size_t)(wn + mt * 32 + l31) * 32 + ch);
            }
        #pragma unroll
        for (int mt = 0; mt < 2; ++mt)
            #pragma unroll
            for (int nt = 0; nt < 2; ++nt)
                #pragma unroll
                for (int kh = 0; kh < 2; ++kh)
                    acc[mt][nt] = __builtin_amdgcn_mfma_f32_32x32x16_bf16(a[mt][kh], b[nt][kh], acc[mt][nt], 0, 0, 0);
        __syncthreads();
    }
    // C/D layout (m74/m101): col = lane&31, row = (reg&3) + 8*(reg>>2) + 4*(lane>>5)
    #pragma unroll
    for (int mt = 0; mt < 2; ++mt)
        #pragma unroll
        for (int nt = 0; nt < 2; ++nt)
            #pragma unroll
            for (int reg = 0; reg < 16; ++reg) {
                int row = tile_m + wm + mt * 32 + (reg & 3) + ((reg >> 2) * 8) + half * 4;
                int col = tile_n + wn + nt * 32 + l31;
                float v = acc[mt][nt][reg];
                if (OUT_BF16) ((bf16*)C)[(size_t)row * N + col] = (bf16)v;
                else          ((float*)C)[(size_t)row * N + col] = v;
            }
}

// ---------------- fused post: per-head RMSNorm+RoPE (Q,K) + V transpose ----------------
__global__ __launch_bounds__(256) void post_kernel(const bf16* __restrict__ qkv,
                                                   const float* __restrict__ qnw, const float* __restrict__ knw,
                                                   const int* __restrict__ positions,
                                                   bf16* __restrict__ Qh, bf16* __restrict__ Kh,
                                                   bf16* __restrict__ VT) {
    int bx = blockIdx.x;
    if (bx < 4096) {
        int tk = bx;                      // token 0..4095
        int b = tk >> 11, s = tk & 2047;
        int wave = threadIdx.x >> 6, lane = threadIdx.x & 63;
        float pos = (float)positions[tk];
        int fi = lane & 15;
        float ang = pos * exp2f(-(float)fi * 1.4533435415278355f);
        float cv = cosf(ang), sv = sinf(ang);

        #pragma unroll
        for (int i = 0; i < 4; ++i) {
            int h = wave + i * 4;
            const bf16* base = qkv + (size_t)tk * NQKV + h * 256;
            float v0 = (float)base[lane], v1 = (float)base[lane + 64];
            float ssq = v0 * v0 + v1 * v1;
            #pragma unroll
            for (int off = 32; off; off >>= 1) ssq += __shfl_xor(ssq, off);
            float rn = rsqrtf(ssq * (1.0f / 128.0f) + 1e-6f);
            float q0 = v0 * rn * (1.0f + qnw[lane]);
            float q1 = v1 * rn * (1.0f + qnw[lane + 64]);
            float other = __shfl_xor(q0, 16);
            float q0r = q0;
            if (lane < 16)      q0r = q0 * cv - other * sv;
            else if (lane < 32) q0r = other * sv + q0 * cv;
            bf16* qout = Qh + ((size_t)(b * NH + h) * SEQ + s) * HD;
            qout[lane] = (bf16)q0r; qout[lane + 64] = (bf16)q1;
        }
        #pragma unroll
        for (int i = 0; i < 2; ++i) {
            int h = wave + i * 4;
            const bf16* base = qkv + (size_t)tk * NQKV + 4096 + h * HD;
            float v0 = (float)base[lane], v1 = (float)base[lane + 64];
            float ssq = v0 * v0 + v1 * v1;
            #pragma unroll
            for (int off = 32; off; off >>= 1) ssq += __shfl_xor(ssq, off);
            float rn = rsqrtf(ssq * (1.0f / 128.0f) + 1e-6f);
            float k0 = v0 * rn * (1.0f + knw[lane]);
            float k1 = v1 * rn * (1.0f + knw[lane + 64]);
            float other = __shfl_xor(k0, 16);
            float k0r = k0;
            if (lane < 16)      k0r = k0 * cv - other * sv;
            else if (lane < 32) k0r = other * sv + k0 * cv;
            bf16* kout = Kh + ((size_t)(b * NKV + h) * SEQ + s) * HD;
            kout[lane] = (bf16)k0r; kout[lane + 64] = (bf16)k1;
        }
    } else {
        int idx = bx - 4096;              // vtrans: 512 blocks
        int bh = idx >> 5, st = idx & 31;
        int b = bh >> 3, h = bh & 7;
        __shared__ float tile[64][129];
        int t = threadIdx.x;
        const bf16* src = qkv + ((size_t)(b * SEQ) + st * 64) * NQKV + 5120 + h * HD;
        #pragma unroll
        for (int i = 0; i < 32; ++i) {
            int ii = i * 256 + t;
            int tok = ii >> 7, d = ii & 127;
            tile[tok][d] = (float)src[(size_t)tok * NQKV + d];
        }
        __syncthreads();
        bf16* dst = VT + (size_t)(b * NKV + h) * HD * SEQ + st * 64;
        #pragma unroll
        for (int i = 0; i < 32; ++i) {
            int ii = i * 256 + t;
            int d = ii >> 6, sx = ii & 63;
            dst[(size_t)d * SEQ + sx] = (bf16)tile[sx][d];
        }
    }
}

// ---------------- flash attention, Br=128, Bc=64, 4 waves x (2x16) q-rows ----------------
// Q in registers; K/V/P in XOR-swizzled LDS; exp2 softmax; qt remapped for balance.
// Each K/V stage feeds 2x the MFMA work vs Br=64; KV traffic and barriers ~halve.
__global__ __launch_bounds__(256, 3) void attn_kernel(const bf16* __restrict__ Qh, const bf16* __restrict__ Kh,
                                                      const bf16* __restrict__ VT, const bf16* __restrict__ qkv,
                                                      const int* __restrict__ amask, bf16* __restrict__ attnb) {
    const int bx = blockIdx.x;              // 512 blocks
    const int hb = bx >> 4;                 // 0..31 = b*16+head
    const int head = hb & 15, b = hb >> 4;
    const int qt = ((bx & 15) + hb) & 15;   // spread qt across co-resident blocks
    const int kvh = head >> 1;
    __shared__ __align__(16) bf16 Ks[64 * 128];     // [row][chunk ^ (row&15)]
    __shared__ __align__(16) bf16 Vs[128 * 64];     // [d][chunk ^ (d&7)]
    __shared__ __align__(16) bf16 Ps[8 * 16 * 64];  // per wave*rf, col ^ ((row>>2)*16)
    const int tid = threadIdx.x, wave = tid >> 6, lane = tid & 63;
    const int quad = lane >> 4, cl = lane & 15;

    // Q fragments in registers: rows qt*128 + rf*64 + wave*16 + cl
    const bf16* qsrc = Qh + ((size_t)(b * NH + head) * SEQ + qt * 128) * HD;
    bf16x8 aq[2][4];
    #pragma unroll
    for (int rf = 0; rf < 2; ++rf)
        #pragma unroll
        for (int kc = 0; kc < 4; ++kc)
            aq[rf][kc] = *(const bf16x8*)(qsrc + (size_t)(rf * 64 + wave * 16 + cl) * HD + kc * 32 + quad * 8);

    float mstate[2][4], lstate[2][4];
    f32x4 oacc[2][8] = {};
    #pragma unroll
    for (int rf = 0; rf < 2; ++rf)
        #pragma unroll
        for (int r = 0; r < 4; ++r) { mstate[rf][r] = -1e30f; lstate[rf][r] = 0.0f; }
    // exp2-domain: scale = (1/sqrt(128)) * log2(e)
    const float scale = 0.08838834764831845f * 1.4426950408889634f;
    const int kmax = 2 * qt + 1;

    for (int kt = 0; kt <= kmax; ++kt) {
        __syncthreads();
        const bf16* ksrc = Kh + ((size_t)(b * NKV + kvh) * SEQ + kt * 64) * HD;
        const bf16* vsrc = VT + (size_t)(b * NKV + kvh) * HD * SEQ + kt * 64;
        #pragma unroll
        for (int j = 0; j < 4; ++j) {
            int s = (j * 4 + wave) * 64 + lane;       // 16B-chunk slot 0..1023
            int rK = s >> 4, cK = s & 15;
            GLOAD_LDS16(ksrc + (size_t)rK * HD + ((cK ^ (rK & 15)) << 3), Ks + (size_t)s * 8);
            int dV = s >> 3, cV = s & 7;
            GLOAD_LDS16(vsrc + (size_t)dV * SEQ + ((cV ^ (dV & 7)) << 3), Vs + (size_t)s * 8);
        }
        __syncthreads();

        // S = Q K^T : 2 x (16 rows) x 64 cols per wave; share bk across rf
        f32x4 sc[2][4] = {};
        #pragma unroll
        for (int nt = 0; nt < 4; ++nt)
            #pragma unroll
            for (int kc = 0; kc < 4; ++kc) {
                bf16x8 bk = *(const bf16x8*)(Ks + (size_t)(nt * 16 + cl) * 128 + (((kc * 4 + quad) ^ cl) << 3));
                sc[0][nt] = __builtin_amdgcn_mfma_f32_16x16x32_bf16(aq[0][kc], bk, sc[0][nt], 0, 0, 0);
                sc[1][nt] = __builtin_amdgcn_mfma_f32_16x16x32_bf16(aq[1][kc], bk, sc[1][nt], 0, 0, 0);
            }

        bool colok[4];
        int kcolb[4];
        #pragma unroll
        for (int nt = 0; nt < 4; ++nt) {
            kcolb[nt] = kt * 64 + nt * 16 + cl;
            colok[nt] = (amask[b * SEQ + kcolb[nt]] != 0);
        }

        #pragma unroll
        for (int rf = 0; rf < 2; ++rf) {
            const int qbase = qt * 128 + rf * 64 + wave * 16 + quad * 4;
            const bool maybe_diag = (kt * 64 + 63) > qbase;   // else whole tile causally valid
            float alpha[4];
            #pragma unroll
            for (int r = 0; r < 4; ++r) {
                float rv[4];
                float tmax = -1e30f;
                #pragma unroll
                for (int nt = 0; nt < 4; ++nt) {
                    float v = sc[rf][nt][r] * scale;
                    bool ok = colok[nt] && (!maybe_diag || (kcolb[nt] <= qbase + r));
                    v = ok ? v : -1e30f;
                    rv[nt] = v;
                    tmax = fmaxf(tmax, v);
                }
                #pragma unroll
                for (int off = 8; off; off >>= 1) tmax = fmaxf(tmax, __shfl_xor(tmax, off));
                float mnew = fmaxf(mstate[rf][r], tmax);
                float al = exp2f(mstate[rf][r] - mnew);
                mstate[rf][r] = mnew; alpha[r] = al;
                float rsum = 0.0f;
                int prow = quad * 4 + r;
                #pragma unroll
                for (int nt = 0; nt < 4; ++nt) {
                    float p = exp2f(rv[nt] - mnew);
                    rsum += p;
                    Ps[(wave * 2 + rf) * 1024 + prow * 64 + ((nt * 16 + cl) ^ (quad << 4))] = (bf16)p;
                }
                #pragma unroll
                for (int off = 8; off; off >>= 1) rsum += __shfl_xor(rsum, off);
                lstate[rf][r] = lstate[rf][r] * al + rsum;
            }
            #pragma unroll
            for (int n2 = 0; n2 < 8; ++n2)
                #pragma unroll
                for (int r = 0; r < 4; ++r) oacc[rf][n2][r] *= alpha[r];
        }

        // O += P V  (share bv across rf)
        bf16x8 ap[2][2];
        #pragma unroll
        for (int rf = 0; rf < 2; ++rf)
            #pragma unroll
            for (int c = 0; c < 2; ++c)
                ap[rf][c] = *(const bf16x8*)(Ps + (wave * 2 + rf) * 1024 + cl * 64 + ((c * 32 + quad * 8) ^ ((cl >> 2) << 4)));
        #pragma unroll
        for (int n2 = 0; n2 < 8; ++n2)
            #pragma unroll
            for (int c = 0; c < 2; ++c) {
                bf16x8 bv = *(const bf16x8*)(Vs + (size_t)(n2 * 16 + cl) * 64 + (((c * 4 + quad) ^ (cl & 7)) << 3));
                oacc[0][n2] = __builtin_amdgcn_mfma_f32_16x16x32_bf16(ap[0][c], bv, oacc[0][n2], 0, 0, 0);
                oacc[1][n2] = __builtin_amdgcn_mfma_f32_16x16x32_bf16(ap[1][c], bv, oacc[1][n2], 0, 0, 0);
            }
    }

    // epilogue: O/l, sigmoid gate, write bf16 [b][s][h*128+d]
    #pragma unroll
    for (int rf = 0; rf < 2; ++rf)
        #pragma unroll
        for (int r = 0; r < 4; ++r) {
            int srow = qt * 128 + rf * 64 + wave * 16 + quad * 4 + r;
            float linv = 1.0f / lstate[rf][r];
            #pragma unroll
            for (int n2 = 0; n2 < 8; ++n2) {
                int d = n2 * 16 + cl;
                float g = (float)qkv[(size_t)(b * SEQ + srow) * NQKV + head * 256 + 128 + d];
                float sig = 1.0f / (1.0f + __expf(-g));
                float v = oacc[rf][n2][r] * linv * sig;
                attnb[(size_t)(b * SEQ + srow) * HID + head * HD + d] = (bf16)v;
            }
        }
}

// ---------------- launch ----------------
extern "C" void kernel_launch(void* const* d_in, const int* in_sizes, int n_in,
                              void* d_out, int out_size, void* d_ws, size_t ws_size,
                              hipStream_t stream) {
    const float* x        = (const float*)d_in[0];
    const int*   amask    = (const int*)d_in[1];
    const int*   positions= (const int*)d_in[2];
    const float* Wq       = (const float*)d_in[3];
    const float* Wk       = (const float*)d_in[4];
    const float* Wv       = (const float*)d_in[5];
    const float* Wo       = (const float*)d_in[6];
    const float* qnw      = (const float*)d_in[7];
    const float* knw      = (const float*)d_in[8];
    float* out = (float*)d_out;
    char* ws = (char*)d_ws;

    bf16* xb    = (bf16*)(ws);                         // 16,777,216 B
    bf16* wqkvT = (bf16*)(ws + 16777216);              // 25,165,824 B
    bf16* woT   = (bf16*)(ws + 41943040);              //  8,388,608 B
    bf16* qkv   = (bf16*)(ws + 50331648);              // 50,331,648 B
    bf16* Qh    = (bf16*)(ws + 100663296);             // 16,777,216 B
    bf16* Kh    = (bf16*)(ws + 117440512);             //  8,388,608 B
    bf16* VT    = (bf16*)(ws + 125829120);             //  8,388,608 B
    bf16* attnb = (bf16*)(ws + 134217728);             // 16,777,216 B -> 150,994,944 total

    prep_kernel<<<12288, 256, 0, stream>>>(x, xb, Wq, Wk, Wv, Wo, wqkvT, woT);
    gemm_bt<true><<<dim3(48, 32), 256, 0, stream>>>(xb, wqkvT, qkv, MTOT, NQKV, HID);
    post_kernel<<<4608, 256, 0, stream>>>(qkv, qnw, knw, positions, Qh, Kh, VT);
    attn_kernel<<<512, 256, 0, stream>>>(Qh, Kh, VT, qkv, amask, attnb);
    gemm_bt<false><<<dim3(16, 32), 256, 0, stream>>>(attnb, woT, out, MTOT, HID, HID);

    (void)in_sizes; (void)n_in; (void)out_size; (void)ws_size;
}

// Round 6
// 469.779 us; speedup vs baseline: 1.3150x; 1.3150x over previous
//
#include <hip/hip_runtime.h>
#include <cstdint>

// ---- types ----
typedef __bf16  bf16;
typedef __bf16  bf16x8 __attribute__((ext_vector_type(8)));
typedef __bf16  bf16x4 __attribute__((ext_vector_type(4)));
typedef float   f32x4  __attribute__((ext_vector_type(4)));
typedef float   f32x16 __attribute__((ext_vector_type(16)));

#define GLOAD_LDS16(g, l) __builtin_amdgcn_global_load_lds( \
    (const __attribute__((address_space(1))) void*)(g),     \
    (__attribute__((address_space(3))) void*)(l), 16, 0, 0)

// dims
#define SEQ   2048
#define HID   2048
#define NH    16
#define NKV   8
#define HD    128
#define NQKV  6144   // 4096 q_all + 1024 k + 1024 v
#define MTOT  4096   // B*SEQ

// ---------------- fused prep: convx + all weight transposes ----------------
__device__ __forceinline__ void transw_body(const float* __restrict__ W, bf16* __restrict__ WT,
                                            int N, int n0, int k0, int t) {
    __shared__ float tile[64][65];
    int tn = t & 63, t4 = t >> 6;
    #pragma unroll
    for (int i = 0; i < 16; ++i) {
        int kk = i * 4 + t4;
        tile[kk][tn] = W[(size_t)(k0 + kk) * N + n0 + tn];
    }
    __syncthreads();
    #pragma unroll
    for (int i = 0; i < 16; ++i) {
        int nn = i * 4 + t4;
        WT[(size_t)(n0 + nn) * HID + k0 + tn] = (bf16)tile[tn][nn];
    }
}

__global__ __launch_bounds__(256) void prep_kernel(const float* __restrict__ x, bf16* __restrict__ xb,
                                                   const float* __restrict__ Wq, const float* __restrict__ Wk,
                                                   const float* __restrict__ Wv, const float* __restrict__ Wo,
                                                   bf16* __restrict__ wqkvT, bf16* __restrict__ woT) {
    int bx = blockIdx.x, t = threadIdx.x;
    if (bx < 8192) {                                   // convx: 4 f32->bf16 per thread
        int i = bx * 256 + t;
        f32x4 v = ((const f32x4*)x)[i];
        bf16x4 o;
        o[0] = (bf16)v[0]; o[1] = (bf16)v[1]; o[2] = (bf16)v[2]; o[3] = (bf16)v[3];
        ((bf16x4*)xb)[i] = o;
    } else if (bx < 8192 + 2048) {                     // Wq: N=4096
        int idx = bx - 8192;
        transw_body(Wq, wqkvT, 4096, (idx & 63) * 64, (idx >> 6) * 64, t);
    } else if (bx < 8192 + 2048 + 512) {               // Wk: N=1024
        int idx = bx - (8192 + 2048);
        transw_body(Wk, wqkvT + (size_t)4096 * HID, 1024, (idx & 15) * 64, (idx >> 4) * 64, t);
    } else if (bx < 8192 + 2048 + 1024) {              // Wv: N=1024
        int idx = bx - (8192 + 2048 + 512);
        transw_body(Wv, wqkvT + (size_t)5120 * HID, 1024, (idx & 15) * 64, (idx >> 4) * 64, t);
    } else {                                           // Wo: N=2048
        int idx = bx - (8192 + 2048 + 1024);
        transw_body(Wo, woT, 2048, (idx & 31) * 64, (idx >> 5) * 64, t);
    }
}

// ---------------- MFMA GEMM: C[M,N] = A[M,K] * Bt[N,K]^T ----------------
// 128x128 tile, BK=32, 4 waves (64x64 quadrants), 32x32x16 MFMA.
// LDS XOR-swizzle: chunk' = chunk ^ ((row>>1)&3) -> conflict-free b128 reads.
template<bool OUT_BF16>
__global__ __launch_bounds__(256) void gemm_bt(const bf16* __restrict__ A, const bf16* __restrict__ Bt,
                                               void* __restrict__ C, int M, int N, int K) {
    __shared__ __align__(16) bf16 As[128 * 32];
    __shared__ __align__(16) bf16 Bs[128 * 32];
    const int tid = threadIdx.x;
    const int wave = tid >> 6, lane = tid & 63;
    const int l31 = lane & 31, half = lane >> 5;
    const int tile_n = blockIdx.x * 128, tile_m = blockIdx.y * 128;
    const int wm = (wave & 1) * 64, wn = (wave >> 1) * 64;
    const int sw = (l31 >> 1) & 3;                      // read-side swizzle
    f32x16 acc[2][2] = {};

    for (int k0 = 0; k0 < K; k0 += 32) {
        #pragma unroll
        for (int j = 0; j < 2; ++j) {
            int c = (j * 4 + wave) * 64 + lane;          // LDS slot 0..511
            int row = c >> 2, kq = c & 3;
            int kqs = kq ^ ((row >> 1) & 3);             // fetch permuted chunk
            GLOAD_LDS16(A  + (size_t)(tile_m + row) * K + k0 + kqs * 8, As + (size_t)(j * 4 + wave) * 512);
            GLOAD_LDS16(Bt + (size_t)(tile_n + row) * K + k0 + kqs * 8, Bs + (size_t)(j * 4 + wave) * 512);
        }
        __syncthreads();
        bf16x8 a[2][2], b[2][2];
        #pragma unroll
        for (int mt = 0; mt < 2; ++mt)
            #pragma unroll
            for (int kh = 0; kh < 2; ++kh) {
                int ch = ((kh * 2 + half) ^ sw) << 3;
                a[mt][kh] = *(const bf16x8*)(As + (size_t)(wm + mt * 32 + l31) * 32 + ch);
                b[mt][kh] = *(const bf16x8*)(Bs + (size_t)(wn + mt * 32 + l31) * 32 + ch);
            }
        #pragma unroll
        for (int mt = 0; mt < 2; ++mt)
            #pragma unroll
            for (int nt = 0; nt < 2; ++nt)
                #pragma unroll
                for (int kh = 0; kh < 2; ++kh)
                    acc[mt][nt] = __builtin_amdgcn_mfma_f32_32x32x16_bf16(a[mt][kh], b[nt][kh], acc[mt][nt], 0, 0, 0);
        __syncthreads();
    }
    // C/D layout (m74/m101): col = lane&31, row = (reg&3) + 8*(reg>>2) + 4*(lane>>5)
    #pragma unroll
    for (int mt = 0; mt < 2; ++mt)
        #pragma unroll
        for (int nt = 0; nt < 2; ++nt)
            #pragma unroll
            for (int reg = 0; reg < 16; ++reg) {
                int row = tile_m + wm + mt * 32 + (reg & 3) + ((reg >> 2) * 8) + half * 4;
                int col = tile_n + wn + nt * 32 + l31;
                float v = acc[mt][nt][reg];
                if (OUT_BF16) ((bf16*)C)[(size_t)row * N + col] = (bf16)v;
                else          ((float*)C)[(size_t)row * N + col] = v;
            }
}

// ---------------- fused post: per-head RMSNorm+RoPE (Q,K) + V transpose ----------------
__global__ __launch_bounds__(256) void post_kernel(const bf16* __restrict__ qkv,
                                                   const float* __restrict__ qnw, const float* __restrict__ knw,
                                                   const int* __restrict__ positions,
                                                   bf16* __restrict__ Qh, bf16* __restrict__ Kh,
                                                   bf16* __restrict__ VT) {
    int bx = blockIdx.x;
    if (bx < 4096) {
        int tk = bx;                      // token 0..4095
        int b = tk >> 11, s = tk & 2047;
        int wave = threadIdx.x >> 6, lane = threadIdx.x & 63;
        float pos = (float)positions[tk];
        int fi = lane & 15;
        float ang = pos * exp2f(-(float)fi * 1.4533435415278355f);
        float cv = cosf(ang), sv = sinf(ang);

        #pragma unroll
        for (int i = 0; i < 4; ++i) {
            int h = wave + i * 4;
            const bf16* base = qkv + (size_t)tk * NQKV + h * 256;
            float v0 = (float)base[lane], v1 = (float)base[lane + 64];
            float ssq = v0 * v0 + v1 * v1;
            #pragma unroll
            for (int off = 32; off; off >>= 1) ssq += __shfl_xor(ssq, off);
            float rn = rsqrtf(ssq * (1.0f / 128.0f) + 1e-6f);
            float q0 = v0 * rn * (1.0f + qnw[lane]);
            float q1 = v1 * rn * (1.0f + qnw[lane + 64]);
            float other = __shfl_xor(q0, 16);
            float q0r = q0;
            if (lane < 16)      q0r = q0 * cv - other * sv;
            else if (lane < 32) q0r = other * sv + q0 * cv;
            bf16* qout = Qh + ((size_t)(b * NH + h) * SEQ + s) * HD;
            qout[lane] = (bf16)q0r; qout[lane + 64] = (bf16)q1;
        }
        #pragma unroll
        for (int i = 0; i < 2; ++i) {
            int h = wave + i * 4;
            const bf16* base = qkv + (size_t)tk * NQKV + 4096 + h * HD;
            float v0 = (float)base[lane], v1 = (float)base[lane + 64];
            float ssq = v0 * v0 + v1 * v1;
            #pragma unroll
            for (int off = 32; off; off >>= 1) ssq += __shfl_xor(ssq, off);
            float rn = rsqrtf(ssq * (1.0f / 128.0f) + 1e-6f);
            float k0 = v0 * rn * (1.0f + knw[lane]);
            float k1 = v1 * rn * (1.0f + knw[lane + 64]);
            float other = __shfl_xor(k0, 16);
            float k0r = k0;
            if (lane < 16)      k0r = k0 * cv - other * sv;
            else if (lane < 32) k0r = other * sv + k0 * cv;
            bf16* kout = Kh + ((size_t)(b * NKV + h) * SEQ + s) * HD;
            kout[lane] = (bf16)k0r; kout[lane + 64] = (bf16)k1;
        }
    } else {
        int idx = bx - 4096;              // vtrans: 512 blocks
        int bh = idx >> 5, st = idx & 31;
        int b = bh >> 3, h = bh & 7;
        __shared__ float tile[64][129];
        int t = threadIdx.x;
        const bf16* src = qkv + ((size_t)(b * SEQ) + st * 64) * NQKV + 5120 + h * HD;
        #pragma unroll
        for (int i = 0; i < 32; ++i) {
            int ii = i * 256 + t;
            int tok = ii >> 7, d = ii & 127;
            tile[tok][d] = (float)src[(size_t)tok * NQKV + d];
        }
        __syncthreads();
        bf16* dst = VT + (size_t)(b * NKV + h) * HD * SEQ + st * 64;
        #pragma unroll
        for (int i = 0; i < 32; ++i) {
            int ii = i * 256 + t;
            int d = ii >> 6, sx = ii & 63;
            dst[(size_t)d * SEQ + sx] = (bf16)tile[sx][d];
        }
    }
}

// ---------------- flash attention, Br=Bc=64, 4 waves x 16 q-rows ----------------
// Round-4 proven structure: Q in registers; K/V/P XOR-swizzled LDS; exp2 softmax;
// qt remapped so co-resident blocks get spread qt (causal balance). No spills.
__global__ __launch_bounds__(256, 4) void attn_kernel(const bf16* __restrict__ Qh, const bf16* __restrict__ Kh,
                                                      const bf16* __restrict__ VT, const bf16* __restrict__ qkv,
                                                      const int* __restrict__ amask, bf16* __restrict__ attnb) {
    const int bx = blockIdx.x;
    const int hb = bx >> 5;                 // 0..31
    const int head = hb & 15, b = hb >> 4;
    const int qt = ((bx & 31) + hb) & 31;   // co-resident blocks get spread qt
    const int kvh = head >> 1;
    __shared__ __align__(16) bf16 Ks[64 * 128];   // [row][chunk ^ (row&15)]
    __shared__ __align__(16) bf16 Vs[128 * 64];   // [d][chunk ^ (d&7)]
    __shared__ __align__(16) bf16 Ps[4 * 16 * 64];// per-wave, col ^ ((row>>2)*16)
    const int tid = threadIdx.x, wave = tid >> 6, lane = tid & 63;
    const int quad = lane >> 4, cl = lane & 15;

    const bf16* qsrc = Qh + ((size_t)(b * NH + head) * SEQ + qt * 64) * HD;
    bf16x8 aq[4];
    #pragma unroll
    for (int kc = 0; kc < 4; ++kc)
        aq[kc] = *(const bf16x8*)(qsrc + (size_t)(wave * 16 + cl) * HD + kc * 32 + quad * 8);

    float mstate[4], lstate[4];
    f32x4 oacc[8] = {};
    #pragma unroll
    for (int r = 0; r < 4; ++r) { mstate[r] = -1e30f; lstate[r] = 0.0f; }
    const int qrow_glob = qt * 64 + wave * 16 + quad * 4;   // + r
    // exp2-domain: scale = (1/sqrt(128)) * log2(e)
    const float scale = 0.08838834764831845f * 1.4426950408889634f;

    for (int kt = 0; kt <= qt; ++kt) {
        __syncthreads();
        const bf16* ksrc = Kh + ((size_t)(b * NKV + kvh) * SEQ + kt * 64) * HD;
        const bf16* vsrc = VT + (size_t)(b * NKV + kvh) * HD * SEQ + kt * 64;
        #pragma unroll
        for (int j = 0; j < 4; ++j) {
            int s = (j * 4 + wave) * 64 + lane;       // 16B-chunk slot 0..1023
            int rK = s >> 4, cK = s & 15;
            GLOAD_LDS16(ksrc + (size_t)rK * HD + ((cK ^ (rK & 15)) << 3), Ks + (size_t)s * 8);
            int dV = s >> 3, cV = s & 7;
            GLOAD_LDS16(vsrc + (size_t)dV * SEQ + ((cV ^ (dV & 7)) << 3), Vs + (size_t)s * 8);
        }
        __syncthreads();

        f32x4 sc[4] = {};
        #pragma unroll
        for (int nt = 0; nt < 4; ++nt)
            #pragma unroll
            for (int kc = 0; kc < 4; ++kc) {
                bf16x8 bk = *(const bf16x8*)(Ks + (size_t)(nt * 16 + cl) * 128 + (((kc * 4 + quad) ^ cl) << 3));
                sc[nt] = __builtin_amdgcn_mfma_f32_16x16x32_bf16(aq[kc], bk, sc[nt], 0, 0, 0);
            }

        bool colok[4];
        int kcolb[4];
        #pragma unroll
        for (int nt = 0; nt < 4; ++nt) {
            kcolb[nt] = kt * 64 + nt * 16 + cl;
            colok[nt] = (amask[b * SEQ + kcolb[nt]] != 0);
        }
        const bool diag = (kt == qt);

        float alpha[4];
        #pragma unroll
        for (int r = 0; r < 4; ++r) {
            float rv[4];
            float tmax = -1e30f;
            #pragma unroll
            for (int nt = 0; nt < 4; ++nt) {
                float v = sc[nt][r] * scale;
                bool ok = colok[nt] && (!diag || (kcolb[nt] <= qrow_glob + r));
                v = ok ? v : -1e30f;
                rv[nt] = v;
                tmax = fmaxf(tmax, v);
            }
            #pragma unroll
            for (int off = 8; off; off >>= 1) tmax = fmaxf(tmax, __shfl_xor(tmax, off));
            float mnew = fmaxf(mstate[r], tmax);
            float al = exp2f(mstate[r] - mnew);
            mstate[r] = mnew; alpha[r] = al;
            float rsum = 0.0f;
            int prow = quad * 4 + r;
            #pragma unroll
            for (int nt = 0; nt < 4; ++nt) {
                float p = exp2f(rv[nt] - mnew);
                rsum += p;
                Ps[wave * 1024 + prow * 64 + ((nt * 16 + cl) ^ (quad << 4))] = (bf16)p;
            }
            #pragma unroll
            for (int off = 8; off; off >>= 1) rsum += __shfl_xor(rsum, off);
            lstate[r] = lstate[r] * al + rsum;
        }
        #pragma unroll
        for (int n2 = 0; n2 < 8; ++n2)
            #pragma unroll
            for (int r = 0; r < 4; ++r) oacc[n2][r] *= alpha[r];

        bf16x8 ap[2];
        #pragma unroll
        for (int c = 0; c < 2; ++c)
            ap[c] = *(const bf16x8*)(Ps + wave * 1024 + cl * 64 + ((c * 32 + quad * 8) ^ ((cl >> 2) << 4)));
        #pragma unroll
        for (int n2 = 0; n2 < 8; ++n2)
            #pragma unroll
            for (int c = 0; c < 2; ++c) {
                bf16x8 bv = *(const bf16x8*)(Vs + (size_t)(n2 * 16 + cl) * 64 + (((c * 4 + quad) ^ (cl & 7)) << 3));
                oacc[n2] = __builtin_amdgcn_mfma_f32_16x16x32_bf16(ap[c], bv, oacc[n2], 0, 0, 0);
            }
    }

    #pragma unroll
    for (int r = 0; r < 4; ++r) {
        int srow = qt * 64 + wave * 16 + quad * 4 + r;
        float linv = 1.0f / lstate[r];
        #pragma unroll
        for (int n2 = 0; n2 < 8; ++n2) {
            int d = n2 * 16 + cl;
            float g = (float)qkv[(size_t)(b * SEQ + srow) * NQKV + head * 256 + 128 + d];
            float sig = 1.0f / (1.0f + __expf(-g));
            float v = oacc[n2][r] * linv * sig;
            attnb[(size_t)(b * SEQ + srow) * HID + head * HD + d] = (bf16)v;
        }
    }
}

// ---------------- launch ----------------
extern "C" void kernel_launch(void* const* d_in, const int* in_sizes, int n_in,
                              void* d_out, int out_size, void* d_ws, size_t ws_size,
                              hipStream_t stream) {
    const float* x        = (const float*)d_in[0];
    const int*   amask    = (const int*)d_in[1];
    const int*   positions= (const int*)d_in[2];
    const float* Wq       = (const float*)d_in[3];
    const float* Wk       = (const float*)d_in[4];
    const float* Wv       = (const float*)d_in[5];
    const float* Wo       = (const float*)d_in[6];
    const float* qnw      = (const float*)d_in[7];
    const float* knw      = (const float*)d_in[8];
    float* out = (float*)d_out;
    char* ws = (char*)d_ws;

    bf16* xb    = (bf16*)(ws);                         // 16,777,216 B
    bf16* wqkvT = (bf16*)(ws + 16777216);              // 25,165,824 B
    bf16* woT   = (bf16*)(ws + 41943040);              //  8,388,608 B
    bf16* qkv   = (bf16*)(ws + 50331648);              // 50,331,648 B
    bf16* Qh    = (bf16*)(ws + 100663296);             // 16,777,216 B
    bf16* Kh    = (bf16*)(ws + 117440512);             //  8,388,608 B
    bf16* VT    = (bf16*)(ws + 125829120);             //  8,388,608 B
    bf16* attnb = (bf16*)(ws + 134217728);             // 16,777,216 B -> 150,994,944 total

    prep_kernel<<<12288, 256, 0, stream>>>(x, xb, Wq, Wk, Wv, Wo, wqkvT, woT);
    gemm_bt<true><<<dim3(48, 32), 256, 0, stream>>>(xb, wqkvT, qkv, MTOT, NQKV, HID);
    post_kernel<<<4608, 256, 0, stream>>>(qkv, qnw, knw, positions, Qh, Kh, VT);
    attn_kernel<<<1024, 256, 0, stream>>>(Qh, Kh, VT, qkv, amask, attnb);
    gemm_bt<false><<<dim3(16, 32), 256, 0, stream>>>(attnb, woT, out, MTOT, HID, HID);

    (void)in_sizes; (void)n_in; (void)out_size; (void)ws_size;
}

// Round 7
// 414.486 us; speedup vs baseline: 1.4904x; 1.1334x over previous
//
#include <hip/hip_runtime.h>
#include <cstdint>

// ---- types ----
typedef __bf16  bf16;
typedef __bf16  bf16x8 __attribute__((ext_vector_type(8)));
typedef __bf16  bf16x4 __attribute__((ext_vector_type(4)));
typedef float   f32x4  __attribute__((ext_vector_type(4)));
typedef float   f32x16 __attribute__((ext_vector_type(16)));

#define GLOAD_LDS16(g, l) __builtin_amdgcn_global_load_lds( \
    (const __attribute__((address_space(1))) void*)(g),     \
    (__attribute__((address_space(3))) void*)(l), 16, 0, 0)

// dims
#define SEQ   2048
#define HID   2048
#define NH    16
#define NKV   8
#define HD    128
#define NQKV  6144   // 4096 q_all + 1024 k + 1024 v
#define MTOT  4096   // B*SEQ

// ---------------- fused prep: convx + all weight transposes ----------------
__device__ __forceinline__ void transw_body(const float* __restrict__ W, bf16* __restrict__ WT,
                                            int N, int n0, int k0, int t) {
    __shared__ float tile[64][65];
    int tn = t & 63, t4 = t >> 6;
    #pragma unroll
    for (int i = 0; i < 16; ++i) {
        int kk = i * 4 + t4;
        tile[kk][tn] = W[(size_t)(k0 + kk) * N + n0 + tn];
    }
    __syncthreads();
    #pragma unroll
    for (int i = 0; i < 16; ++i) {
        int nn = i * 4 + t4;
        WT[(size_t)(n0 + nn) * HID + k0 + tn] = (bf16)tile[tn][nn];
    }
}

__global__ __launch_bounds__(256) void prep_kernel(const float* __restrict__ x, bf16* __restrict__ xb,
                                                   const float* __restrict__ Wq, const float* __restrict__ Wk,
                                                   const float* __restrict__ Wv, const float* __restrict__ Wo,
                                                   bf16* __restrict__ wqkvT, bf16* __restrict__ woT) {
    int bx = blockIdx.x, t = threadIdx.x;
    if (bx < 8192) {                                   // convx: 4 f32->bf16 per thread
        int i = bx * 256 + t;
        f32x4 v = ((const f32x4*)x)[i];
        bf16x4 o;
        o[0] = (bf16)v[0]; o[1] = (bf16)v[1]; o[2] = (bf16)v[2]; o[3] = (bf16)v[3];
        ((bf16x4*)xb)[i] = o;
    } else if (bx < 8192 + 2048) {                     // Wq: N=4096
        int idx = bx - 8192;
        transw_body(Wq, wqkvT, 4096, (idx & 63) * 64, (idx >> 6) * 64, t);
    } else if (bx < 8192 + 2048 + 512) {               // Wk: N=1024
        int idx = bx - (8192 + 2048);
        transw_body(Wk, wqkvT + (size_t)4096 * HID, 1024, (idx & 15) * 64, (idx >> 4) * 64, t);
    } else if (bx < 8192 + 2048 + 1024) {              // Wv: N=1024
        int idx = bx - (8192 + 2048 + 512);
        transw_body(Wv, wqkvT + (size_t)5120 * HID, 1024, (idx & 15) * 64, (idx >> 4) * 64, t);
    } else {                                           // Wo: N=2048
        int idx = bx - (8192 + 2048 + 1024);
        transw_body(Wo, woT, 2048, (idx & 31) * 64, (idx >> 5) * 64, t);
    }
}

// ---------------- MFMA GEMM: C[M,N] = A[M,K] * Bt[N,K]^T ----------------
// 128x128 tile, BK=32, 4 waves (64x64 quadrants), 32x32x16 MFMA.
// LDS XOR-swizzle: chunk' = chunk ^ ((row>>1)&3) -> conflict-free b128 reads.
template<bool OUT_BF16>
__global__ __launch_bounds__(256) void gemm_bt(const bf16* __restrict__ A, const bf16* __restrict__ Bt,
                                               void* __restrict__ C, int M, int N, int K) {
    __shared__ __align__(16) bf16 As[128 * 32];
    __shared__ __align__(16) bf16 Bs[128 * 32];
    const int tid = threadIdx.x;
    const int wave = tid >> 6, lane = tid & 63;
    const int l31 = lane & 31, half = lane >> 5;
    const int tile_n = blockIdx.x * 128, tile_m = blockIdx.y * 128;
    const int wm = (wave & 1) * 64, wn = (wave >> 1) * 64;
    const int sw = (l31 >> 1) & 3;                      // read-side swizzle
    f32x16 acc[2][2] = {};

    for (int k0 = 0; k0 < K; k0 += 32) {
        #pragma unroll
        for (int j = 0; j < 2; ++j) {
            int c = (j * 4 + wave) * 64 + lane;          // LDS slot 0..511
            int row = c >> 2, kq = c & 3;
            int kqs = kq ^ ((row >> 1) & 3);             // fetch permuted chunk
            GLOAD_LDS16(A  + (size_t)(tile_m + row) * K + k0 + kqs * 8, As + (size_t)(j * 4 + wave) * 512);
            GLOAD_LDS16(Bt + (size_t)(tile_n + row) * K + k0 + kqs * 8, Bs + (size_t)(j * 4 + wave) * 512);
        }
        __syncthreads();
        bf16x8 a[2][2], b[2][2];
        #pragma unroll
        for (int mt = 0; mt < 2; ++mt)
            #pragma unroll
            for (int kh = 0; kh < 2; ++kh) {
                int ch = ((kh * 2 + half) ^ sw) << 3;
                a[mt][kh] = *(const bf16x8*)(As + (size_t)(wm + mt * 32 + l31) * 32 + ch);
                b[mt][kh] = *(const bf16x8*)(Bs + (size_t)(wn + mt * 32 + l31) * 32 + ch);
            }
        #pragma unroll
        for (int mt = 0; mt < 2; ++mt)
            #pragma unroll
            for (int nt = 0; nt < 2; ++nt)
                #pragma unroll
                for (int kh = 0; kh < 2; ++kh)
                    acc[mt][nt] = __builtin_amdgcn_mfma_f32_32x32x16_bf16(a[mt][kh], b[nt][kh], acc[mt][nt], 0, 0, 0);
        __syncthreads();
    }
    // C/D layout (m74/m101): col = lane&31, row = (reg&3) + 8*(reg>>2) + 4*(lane>>5)
    #pragma unroll
    for (int mt = 0; mt < 2; ++mt)
        #pragma unroll
        for (int nt = 0; nt < 2; ++nt)
            #pragma unroll
            for (int reg = 0; reg < 16; ++reg) {
                int row = tile_m + wm + mt * 32 + (reg & 3) + ((reg >> 2) * 8) + half * 4;
                int col = tile_n + wn + nt * 32 + l31;
                float v = acc[mt][nt][reg];
                if (OUT_BF16) ((bf16*)C)[(size_t)row * N + col] = (bf16)v;
                else          ((float*)C)[(size_t)row * N + col] = v;
            }
}

// ---------------- fused post: per-head RMSNorm+RoPE (Q,K) + V transpose ----------------
__global__ __launch_bounds__(256) void post_kernel(const bf16* __restrict__ qkv,
                                                   const float* __restrict__ qnw, const float* __restrict__ knw,
                                                   const int* __restrict__ positions,
                                                   bf16* __restrict__ Qh, bf16* __restrict__ Kh,
                                                   bf16* __restrict__ VT) {
    int bx = blockIdx.x;
    if (bx < 4096) {
        int tk = bx;                      // token 0..4095
        int b = tk >> 11, s = tk & 2047;
        int wave = threadIdx.x >> 6, lane = threadIdx.x & 63;
        float pos = (float)positions[tk];
        int fi = lane & 15;
        float ang = pos * exp2f(-(float)fi * 1.4533435415278355f);
        float cv = cosf(ang), sv = sinf(ang);

        #pragma unroll
        for (int i = 0; i < 4; ++i) {
            int h = wave + i * 4;
            const bf16* base = qkv + (size_t)tk * NQKV + h * 256;
            float v0 = (float)base[lane], v1 = (float)base[lane + 64];
            float ssq = v0 * v0 + v1 * v1;
            #pragma unroll
            for (int off = 32; off; off >>= 1) ssq += __shfl_xor(ssq, off);
            float rn = rsqrtf(ssq * (1.0f / 128.0f) + 1e-6f);
            float q0 = v0 * rn * (1.0f + qnw[lane]);
            float q1 = v1 * rn * (1.0f + qnw[lane + 64]);
            float other = __shfl_xor(q0, 16);
            float q0r = q0;
            if (lane < 16)      q0r = q0 * cv - other * sv;
            else if (lane < 32) q0r = other * sv + q0 * cv;
            bf16* qout = Qh + ((size_t)(b * NH + h) * SEQ + s) * HD;
            qout[lane] = (bf16)q0r; qout[lane + 64] = (bf16)q1;
        }
        #pragma unroll
        for (int i = 0; i < 2; ++i) {
            int h = wave + i * 4;
            const bf16* base = qkv + (size_t)tk * NQKV + 4096 + h * HD;
            float v0 = (float)base[lane], v1 = (float)base[lane + 64];
            float ssq = v0 * v0 + v1 * v1;
            #pragma unroll
            for (int off = 32; off; off >>= 1) ssq += __shfl_xor(ssq, off);
            float rn = rsqrtf(ssq * (1.0f / 128.0f) + 1e-6f);
            float k0 = v0 * rn * (1.0f + knw[lane]);
            float k1 = v1 * rn * (1.0f + knw[lane + 64]);
            float other = __shfl_xor(k0, 16);
            float k0r = k0;
            if (lane < 16)      k0r = k0 * cv - other * sv;
            else if (lane < 32) k0r = other * sv + k0 * cv;
            bf16* kout = Kh + ((size_t)(b * NKV + h) * SEQ + s) * HD;
            kout[lane] = (bf16)k0r; kout[lane + 64] = (bf16)k1;
        }
    } else {
        int idx = bx - 4096;              // vtrans: 512 blocks
        int bh = idx >> 5, st = idx & 31;
        int b = bh >> 3, h = bh & 7;
        __shared__ float tile[64][129];
        int t = threadIdx.x;
        const bf16* src = qkv + ((size_t)(b * SEQ) + st * 64) * NQKV + 5120 + h * HD;
        #pragma unroll
        for (int i = 0; i < 32; ++i) {
            int ii = i * 256 + t;
            int tok = ii >> 7, d = ii & 127;
            tile[tok][d] = (float)src[(size_t)tok * NQKV + d];
        }
        __syncthreads();
        bf16* dst = VT + (size_t)(b * NKV + h) * HD * SEQ + st * 64;
        #pragma unroll
        for (int i = 0; i < 32; ++i) {
            int ii = i * 256 + t;
            int d = ii >> 6, sx = ii & 63;
            dst[(size_t)d * SEQ + sx] = (bf16)tile[sx][d];
        }
    }
}

// ---------------- flash attention, Br=128, Bc=64, 8 waves x 16 q-rows ----------------
// Fixed-max softmax (Q,K are RMS-normalized: |score*scale*log2e| <= ~18.3 < M=20,
// softmax is shift-invariant -> drop max reduction, alpha rescale, per-kt l-sum).
// Per-wave register state identical to the proven Br=64 kernel (no spill).
// K/V staged once per 128 Q-rows; qt pairing (qt, 15-qt) balances co-resident blocks.
__global__ __launch_bounds__(512, 4) void attn_kernel(const bf16* __restrict__ Qh, const bf16* __restrict__ Kh,
                                                      const bf16* __restrict__ VT, const bf16* __restrict__ qkv,
                                                      const int* __restrict__ amask, bf16* __restrict__ attnb) {
    const int bx = blockIdx.x;              // 512 blocks
    const int hb = (bx >> 4) & 31;          // b*16+head
    const int head = hb & 15, b = hb >> 4;
    int q0 = ((bx & 15) + hb) & 15;
    const int qt = (bx & 256) ? (15 - q0) : q0;   // pair sums constant work
    const int kvh = head >> 1;
    __shared__ __align__(16) bf16 Ks[64 * 128];     // [row][chunk ^ (row&15)]
    __shared__ __align__(16) bf16 Vs[128 * 64];     // [d][chunk ^ (d&7)]
    __shared__ __align__(16) bf16 Ps[8 * 16 * 64];  // per-wave, col ^ ((row>>2)*16)
    const int tid = threadIdx.x, wave = tid >> 6, lane = tid & 63;
    const int quad = lane >> 4, cl = lane & 15;

    // Q fragments in registers: rows qt*128 + wave*16 + cl
    const bf16* qsrc = Qh + ((size_t)(b * NH + head) * SEQ + qt * 128) * HD;
    bf16x8 aq[4];
    #pragma unroll
    for (int kc = 0; kc < 4; ++kc)
        aq[kc] = *(const bf16x8*)(qsrc + (size_t)(wave * 16 + cl) * HD + kc * 32 + quad * 8);

    float lstate[4] = {0.0f, 0.0f, 0.0f, 0.0f};
    f32x4 oacc[8] = {};
    const int qrow_glob = qt * 128 + wave * 16 + quad * 4;  // + r
    // exp2-domain: scale = (1/sqrt(128)) * log2(e); fixed max M = 20
    const float scale = 0.08838834764831845f * 1.4426950408889634f;
    const float M = 20.0f;
    const int kmax = 2 * qt + 1;

    for (int kt = 0; kt <= kmax; ++kt) {
        __syncthreads();
        const bf16* ksrc = Kh + ((size_t)(b * NKV + kvh) * SEQ + kt * 64) * HD;
        const bf16* vsrc = VT + (size_t)(b * NKV + kvh) * HD * SEQ + kt * 64;
        #pragma unroll
        for (int j = 0; j < 2; ++j) {
            int s = j * 512 + tid;                    // 16B-chunk slot 0..1023
            int rK = s >> 4, cK = s & 15;
            GLOAD_LDS16(ksrc + (size_t)rK * HD + ((cK ^ (rK & 15)) << 3), Ks + (size_t)s * 8);
            int dV = s >> 3, cV = s & 7;
            GLOAD_LDS16(vsrc + (size_t)dV * SEQ + ((cV ^ (dV & 7)) << 3), Vs + (size_t)s * 8);
        }
        __syncthreads();

        f32x4 sc[4] = {};
        #pragma unroll
        for (int nt = 0; nt < 4; ++nt)
            #pragma unroll
            for (int kc = 0; kc < 4; ++kc) {
                bf16x8 bk = *(const bf16x8*)(Ks + (size_t)(nt * 16 + cl) * 128 + (((kc * 4 + quad) ^ cl) << 3));
                sc[nt] = __builtin_amdgcn_mfma_f32_16x16x32_bf16(aq[kc], bk, sc[nt], 0, 0, 0);
            }

        #pragma unroll
        for (int nt = 0; nt < 4; ++nt) {
            int kcol = kt * 64 + nt * 16 + cl;
            bool cok = (amask[b * SEQ + kcol] != 0);
            #pragma unroll
            for (int r = 0; r < 4; ++r) {
                bool ok = cok && (kcol <= qrow_glob + r);
                float p = ok ? exp2f(sc[nt][r] * scale - M) : 0.0f;
                lstate[r] += p;
                Ps[wave * 1024 + (quad * 4 + r) * 64 + ((nt * 16 + cl) ^ (quad << 4))] = (bf16)p;
            }
        }

        bf16x8 ap[2];
        #pragma unroll
        for (int c = 0; c < 2; ++c)
            ap[c] = *(const bf16x8*)(Ps + wave * 1024 + cl * 64 + ((c * 32 + quad * 8) ^ ((cl >> 2) << 4)));
        #pragma unroll
        for (int n2 = 0; n2 < 8; ++n2)
            #pragma unroll
            for (int c = 0; c < 2; ++c) {
                bf16x8 bv = *(const bf16x8*)(Vs + (size_t)(n2 * 16 + cl) * 64 + (((c * 4 + quad) ^ (cl & 7)) << 3));
                oacc[n2] = __builtin_amdgcn_mfma_f32_16x16x32_bf16(ap[c], bv, oacc[n2], 0, 0, 0);
            }
    }

    // epilogue: reduce l across the 16 col-lanes once, O/l, sigmoid gate, store
    #pragma unroll
    for (int r = 0; r < 4; ++r) {
        #pragma unroll
        for (int off = 8; off; off >>= 1) lstate[r] += __shfl_xor(lstate[r], off);
        int srow = qt * 128 + wave * 16 + quad * 4 + r;
        float linv = 1.0f / lstate[r];
        #pragma unroll
        for (int n2 = 0; n2 < 8; ++n2) {
            int d = n2 * 16 + cl;
            float g = (float)qkv[(size_t)(b * SEQ + srow) * NQKV + head * 256 + 128 + d];
            float sig = 1.0f / (1.0f + __expf(-g));
            float v = oacc[n2][r] * linv * sig;
            attnb[(size_t)(b * SEQ + srow) * HID + head * HD + d] = (bf16)v;
        }
    }
}

// ---------------- launch ----------------
extern "C" void kernel_launch(void* const* d_in, const int* in_sizes, int n_in,
                              void* d_out, int out_size, void* d_ws, size_t ws_size,
                              hipStream_t stream) {
    const float* x        = (const float*)d_in[0];
    const int*   amask    = (const int*)d_in[1];
    const int*   positions= (const int*)d_in[2];
    const float* Wq       = (const float*)d_in[3];
    const float* Wk       = (const float*)d_in[4];
    const float* Wv       = (const float*)d_in[5];
    const float* Wo       = (const float*)d_in[6];
    const float* qnw      = (const float*)d_in[7];
    const float* knw      = (const float*)d_in[8];
    float* out = (float*)d_out;
    char* ws = (char*)d_ws;

    bf16* xb    = (bf16*)(ws);                         // 16,777,216 B
    bf16* wqkvT = (bf16*)(ws + 16777216);              // 25,165,824 B
    bf16* woT   = (bf16*)(ws + 41943040);              //  8,388,608 B
    bf16* qkv   = (bf16*)(ws + 50331648);              // 50,331,648 B
    bf16* Qh    = (bf16*)(ws + 100663296);             // 16,777,216 B
    bf16* Kh    = (bf16*)(ws + 117440512);             //  8,388,608 B
    bf16* VT    = (bf16*)(ws + 125829120);             //  8,388,608 B
    bf16* attnb = (bf16*)(ws + 134217728);             // 16,777,216 B -> 150,994,944 total

    prep_kernel<<<12288, 256, 0, stream>>>(x, xb, Wq, Wk, Wv, Wo, wqkvT, woT);
    gemm_bt<true><<<dim3(48, 32), 256, 0, stream>>>(xb, wqkvT, qkv, MTOT, NQKV, HID);
    post_kernel<<<4608, 256, 0, stream>>>(qkv, qnw, knw, positions, Qh, Kh, VT);
    attn_kernel<<<512, 512, 0, stream>>>(Qh, Kh, VT, qkv, amask, attnb);
    gemm_bt<false><<<dim3(16, 32), 256, 0, stream>>>(attnb, woT, out, MTOT, HID, HID);

    (void)in_sizes; (void)n_in; (void)out_size; (void)ws_size;
}

// Round 8
// 396.400 us; speedup vs baseline: 1.5584x; 1.0456x over previous
//
#include <hip/hip_runtime.h>
#include <cstdint>

// ---- types ----
typedef __bf16  bf16;
typedef __bf16  bf16x8 __attribute__((ext_vector_type(8)));
typedef __bf16  bf16x4 __attribute__((ext_vector_type(4)));
typedef __bf16  bf16x2 __attribute__((ext_vector_type(2)));
typedef float   f32x4  __attribute__((ext_vector_type(4)));
typedef float   f32x16 __attribute__((ext_vector_type(16)));

#define GLOAD_LDS16(g, l) __builtin_amdgcn_global_load_lds( \
    (const __attribute__((address_space(1))) void*)(g),     \
    (__attribute__((address_space(3))) void*)(l), 16, 0, 0)

// dims
#define SEQ   2048
#define HID   2048
#define NH    16
#define NKV   8
#define HD    128
#define NQKV  6144   // 4096 q_all + 1024 k + 1024 v
#define MTOT  4096   // B*SEQ

// ---------------- fused prep: convx + all weight transposes ----------------
__device__ __forceinline__ void transw_body(const float* __restrict__ W, bf16* __restrict__ WT,
                                            int N, int n0, int k0, int t) {
    __shared__ float tile[64][65];
    int tn = t & 63, t4 = t >> 6;
    #pragma unroll
    for (int i = 0; i < 16; ++i) {
        int kk = i * 4 + t4;
        tile[kk][tn] = W[(size_t)(k0 + kk) * N + n0 + tn];
    }
    __syncthreads();
    #pragma unroll
    for (int i = 0; i < 16; ++i) {
        int nn = i * 4 + t4;
        WT[(size_t)(n0 + nn) * HID + k0 + tn] = (bf16)tile[tn][nn];
    }
}

__global__ __launch_bounds__(256) void prep_kernel(const float* __restrict__ x, bf16* __restrict__ xb,
                                                   const float* __restrict__ Wq, const float* __restrict__ Wk,
                                                   const float* __restrict__ Wv, const float* __restrict__ Wo,
                                                   bf16* __restrict__ wqkvT, bf16* __restrict__ woT) {
    int bx = blockIdx.x, t = threadIdx.x;
    if (bx < 8192) {                                   // convx: 4 f32->bf16 per thread
        int i = bx * 256 + t;
        f32x4 v = ((const f32x4*)x)[i];
        bf16x4 o;
        o[0] = (bf16)v[0]; o[1] = (bf16)v[1]; o[2] = (bf16)v[2]; o[3] = (bf16)v[3];
        ((bf16x4*)xb)[i] = o;
    } else if (bx < 8192 + 2048) {                     // Wq: N=4096
        int idx = bx - 8192;
        transw_body(Wq, wqkvT, 4096, (idx & 63) * 64, (idx >> 6) * 64, t);
    } else if (bx < 8192 + 2048 + 512) {               // Wk: N=1024
        int idx = bx - (8192 + 2048);
        transw_body(Wk, wqkvT + (size_t)4096 * HID, 1024, (idx & 15) * 64, (idx >> 4) * 64, t);
    } else if (bx < 8192 + 2048 + 1024) {              // Wv: N=1024
        int idx = bx - (8192 + 2048 + 512);
        transw_body(Wv, wqkvT + (size_t)5120 * HID, 1024, (idx & 15) * 64, (idx >> 4) * 64, t);
    } else {                                           // Wo: N=2048
        int idx = bx - (8192 + 2048 + 1024);
        transw_body(Wo, woT, 2048, (idx & 31) * 64, (idx >> 5) * 64, t);
    }
}

// ---------------- MFMA GEMM: C[M,N] = A[M,K] * Bt[N,K]^T ----------------
// 128x128 tile, BK=64 (half the barriers of BK=32), 4 waves (64x64 quadrants),
// 32x32x16 MFMA. LDS 8-chunk rows, XOR swizzle: store chunk c^(row&7),
// read chunk (ks*2+half)^(l31&7) -> 8 lanes/granule (conflict-free minimum).
template<bool OUT_BF16>
__global__ __launch_bounds__(256) void gemm_bt(const bf16* __restrict__ A, const bf16* __restrict__ Bt,
                                               void* __restrict__ C, int M, int N, int K) {
    __shared__ __align__(16) bf16 As[128 * 64];   // 16 KB
    __shared__ __align__(16) bf16 Bs[128 * 64];   // 16 KB
    const int tid = threadIdx.x;
    const int wave = tid >> 6, lane = tid & 63;
    const int l31 = lane & 31, half = lane >> 5;
    const int tile_n = blockIdx.x * 128, tile_m = blockIdx.y * 128;
    const int wm = (wave & 1) * 64, wn = (wave >> 1) * 64;
    const int sw = l31 & 7;                             // read-side swizzle
    f32x16 acc[2][2] = {};

    for (int k0 = 0; k0 < K; k0 += 64) {
        __syncthreads();
        #pragma unroll
        for (int j = 0; j < 4; ++j) {
            int s = j * 256 + tid;                       // LDS slot 0..1023 (16B each)
            int row = s >> 3, c = s & 7;
            int cs = c ^ (row & 7);                      // fetch permuted chunk
            GLOAD_LDS16(A  + (size_t)(tile_m + row) * K + k0 + (cs << 3), As + (size_t)s * 8);
            GLOAD_LDS16(Bt + (size_t)(tile_n + row) * K + k0 + (cs << 3), Bs + (size_t)s * 8);
        }
        __syncthreads();
        #pragma unroll
        for (int ks = 0; ks < 4; ++ks) {
            int ch = ((ks * 2 + half) ^ sw) << 3;
            bf16x8 a0 = *(const bf16x8*)(As + (size_t)(wm + l31) * 64 + ch);
            bf16x8 a1 = *(const bf16x8*)(As + (size_t)(wm + 32 + l31) * 64 + ch);
            bf16x8 b0 = *(const bf16x8*)(Bs + (size_t)(wn + l31) * 64 + ch);
            bf16x8 b1 = *(const bf16x8*)(Bs + (size_t)(wn + 32 + l31) * 64 + ch);
            acc[0][0] = __builtin_amdgcn_mfma_f32_32x32x16_bf16(a0, b0, acc[0][0], 0, 0, 0);
            acc[0][1] = __builtin_amdgcn_mfma_f32_32x32x16_bf16(a0, b1, acc[0][1], 0, 0, 0);
            acc[1][0] = __builtin_amdgcn_mfma_f32_32x32x16_bf16(a1, b0, acc[1][0], 0, 0, 0);
            acc[1][1] = __builtin_amdgcn_mfma_f32_32x32x16_bf16(a1, b1, acc[1][1], 0, 0, 0);
        }
    }
    // C/D layout (m74/m101): col = lane&31, row = (reg&3) + 8*(reg>>2) + 4*(lane>>5)
    #pragma unroll
    for (int mt = 0; mt < 2; ++mt)
        #pragma unroll
        for (int nt = 0; nt < 2; ++nt)
            #pragma unroll
            for (int reg = 0; reg < 16; ++reg) {
                int row = tile_m + wm + mt * 32 + (reg & 3) + ((reg >> 2) * 8) + half * 4;
                int col = tile_n + wn + nt * 32 + l31;
                float v = acc[mt][nt][reg];
                if (OUT_BF16) ((bf16*)C)[(size_t)row * N + col] = (bf16)v;
                else          ((float*)C)[(size_t)row * N + col] = v;
            }
}

// ---------------- fused post: per-head RMSNorm+RoPE (Q,K) + V transpose ----------------
// 2 elems/lane (bf16x2 loads/stores); RoPE partner via shfl_xor(8).
__global__ __launch_bounds__(256) void post_kernel(const bf16* __restrict__ qkv,
                                                   const float* __restrict__ qnw, const float* __restrict__ knw,
                                                   const int* __restrict__ positions,
                                                   bf16* __restrict__ Qh, bf16* __restrict__ Kh,
                                                   bf16* __restrict__ VT) {
    int bx = blockIdx.x;
    if (bx < 4096) {
        int tk = bx;                      // token 0..4095
        int b = tk >> 11, s = tk & 2047;
        int wave = threadIdx.x >> 6, lane = threadIdx.x & 63;
        int e0 = lane * 2, e1 = e0 + 1;
        float pos = (float)positions[tk];
        const float L = 1.4533435415278355f;    // log2(theta)/16
        float a0 = pos * exp2f(-(float)(e0 & 15) * L);
        float a1 = pos * exp2f(-(float)(e1 & 15) * L);
        float cv0 = cosf(a0), sv0 = sinf(a0);
        float cv1 = cosf(a1), sv1 = sinf(a1);
        float qw0 = 1.0f + qnw[e0], qw1 = 1.0f + qnw[e1];
        float kw0 = 1.0f + knw[e0], kw1 = 1.0f + knw[e1];

        #pragma unroll
        for (int i = 0; i < 6; ++i) {
            // i<4: q heads {wave,wave+4,wave+8,wave+12}; i>=4: k heads {wave,wave+4}
            bool isq = (i < 4);
            int h = wave + (isq ? i : (i - 4)) * 4;
            const bf16* base = qkv + (size_t)tk * NQKV + (isq ? h * 256 : 4096 + h * HD);
            bf16x2 v = *(const bf16x2*)(base + e0);
            float f0 = (float)v[0], f1 = (float)v[1];
            float ssq = f0 * f0 + f1 * f1;
            #pragma unroll
            for (int off = 32; off; off >>= 1) ssq += __shfl_xor(ssq, off);
            float rn = rsqrtf(ssq * (1.0f / 128.0f) + 1e-6f);
            float w0 = isq ? qw0 : kw0, w1 = isq ? qw1 : kw1;
            float x0 = f0 * rn * w0, x1 = f1 * rn * w1;
            float p0 = __shfl_xor(x0, 8), p1 = __shfl_xor(x1, 8);
            float r0 = x0, r1 = x1;
            if (lane < 8)       { r0 = x0 * cv0 - p0 * sv0; r1 = x1 * cv1 - p1 * sv1; }
            else if (lane < 16) { r0 = p0 * sv0 + x0 * cv0; r1 = p1 * sv1 + x1 * cv1; }
            bf16x2 o; o[0] = (bf16)r0; o[1] = (bf16)r1;
            bf16* dst = isq ? (Qh + ((size_t)(b * NH + h) * SEQ + s) * HD)
                            : (Kh + ((size_t)(b * NKV + h) * SEQ + s) * HD);
            *(bf16x2*)(dst + e0) = o;
        }
    } else {
        int idx = bx - 4096;              // vtrans: 512 blocks
        int bh = idx >> 5, st = idx & 31;
        int b = bh >> 3, h = bh & 7;
        __shared__ float tile[64][129];
        int t = threadIdx.x;
        const bf16* src = qkv + ((size_t)(b * SEQ) + st * 64) * NQKV + 5120 + h * HD;
        #pragma unroll
        for (int i = 0; i < 32; ++i) {
            int ii = i * 256 + t;
            int tok = ii >> 7, d = ii & 127;
            tile[tok][d] = (float)src[(size_t)tok * NQKV + d];
        }
        __syncthreads();
        bf16* dst = VT + (size_t)(b * NKV + h) * HD * SEQ + st * 64;
        #pragma unroll
        for (int i = 0; i < 32; ++i) {
            int ii = i * 256 + t;
            int d = ii >> 6, sx = ii & 63;
            dst[(size_t)d * SEQ + sx] = (bf16)tile[sx][d];
        }
    }
}

// ---------------- flash attention, Br=128, Bc=64, 8 waves x 16 q-rows ----------------
// Fixed-max softmax (Q,K RMS-normalized: |score*scale*log2e| <= ~18.3 < M=20).
// K/V/P XOR-swizzled LDS; qt pairing (qt, 15-qt) balances co-resident blocks.
__global__ __launch_bounds__(512, 4) void attn_kernel(const bf16* __restrict__ Qh, const bf16* __restrict__ Kh,
                                                      const bf16* __restrict__ VT, const bf16* __restrict__ qkv,
                                                      const int* __restrict__ amask, bf16* __restrict__ attnb) {
    const int bx = blockIdx.x;              // 512 blocks
    const int hb = (bx >> 4) & 31;          // b*16+head
    const int head = hb & 15, b = hb >> 4;
    int q0 = ((bx & 15) + hb) & 15;
    const int qt = (bx & 256) ? (15 - q0) : q0;   // pair sums constant work
    const int kvh = head >> 1;
    __shared__ __align__(16) bf16 Ks[64 * 128];     // [row][chunk ^ (row&15)]
    __shared__ __align__(16) bf16 Vs[128 * 64];     // [d][chunk ^ (d&7)]
    __shared__ __align__(16) bf16 Ps[8 * 16 * 64];  // per-wave, col ^ ((row>>2)*16)
    const int tid = threadIdx.x, wave = tid >> 6, lane = tid & 63;
    const int quad = lane >> 4, cl = lane & 15;

    // Q fragments in registers: rows qt*128 + wave*16 + cl
    const bf16* qsrc = Qh + ((size_t)(b * NH + head) * SEQ + qt * 128) * HD;
    bf16x8 aq[4];
    #pragma unroll
    for (int kc = 0; kc < 4; ++kc)
        aq[kc] = *(const bf16x8*)(qsrc + (size_t)(wave * 16 + cl) * HD + kc * 32 + quad * 8);

    float lstate[4] = {0.0f, 0.0f, 0.0f, 0.0f};
    f32x4 oacc[8] = {};
    const int qrow_glob = qt * 128 + wave * 16 + quad * 4;  // + r
    // exp2-domain: scale = (1/sqrt(128)) * log2(e); fixed max M = 20
    const float scale = 0.08838834764831845f * 1.4426950408889634f;
    const float M = 20.0f;
    const int kmax = 2 * qt + 1;

    for (int kt = 0; kt <= kmax; ++kt) {
        __syncthreads();
        const bf16* ksrc = Kh + ((size_t)(b * NKV + kvh) * SEQ + kt * 64) * HD;
        const bf16* vsrc = VT + (size_t)(b * NKV + kvh) * HD * SEQ + kt * 64;
        #pragma unroll
        for (int j = 0; j < 2; ++j) {
            int s = j * 512 + tid;                    // 16B-chunk slot 0..1023
            int rK = s >> 4, cK = s & 15;
            GLOAD_LDS16(ksrc + (size_t)rK * HD + ((cK ^ (rK & 15)) << 3), Ks + (size_t)s * 8);
            int dV = s >> 3, cV = s & 7;
            GLOAD_LDS16(vsrc + (size_t)dV * SEQ + ((cV ^ (dV & 7)) << 3), Vs + (size_t)s * 8);
        }
        __syncthreads();

        f32x4 sc[4] = {};
        #pragma unroll
        for (int nt = 0; nt < 4; ++nt)
            #pragma unroll
            for (int kc = 0; kc < 4; ++kc) {
                bf16x8 bk = *(const bf16x8*)(Ks + (size_t)(nt * 16 + cl) * 128 + (((kc * 4 + quad) ^ cl) << 3));
                sc[nt] = __builtin_amdgcn_mfma_f32_16x16x32_bf16(aq[kc], bk, sc[nt], 0, 0, 0);
            }

        #pragma unroll
        for (int nt = 0; nt < 4; ++nt) {
            int kcol = kt * 64 + nt * 16 + cl;
            bool cok = (amask[b * SEQ + kcol] != 0);
            #pragma unroll
            for (int r = 0; r < 4; ++r) {
                bool ok = cok && (kcol <= qrow_glob + r);
                float p = ok ? exp2f(sc[nt][r] * scale - M) : 0.0f;
                lstate[r] += p;
                Ps[wave * 1024 + (quad * 4 + r) * 64 + ((nt * 16 + cl) ^ (quad << 4))] = (bf16)p;
            }
        }

        bf16x8 ap[2];
        #pragma unroll
        for (int c = 0; c < 2; ++c)
            ap[c] = *(const bf16x8*)(Ps + wave * 1024 + cl * 64 + ((c * 32 + quad * 8) ^ ((cl >> 2) << 4)));
        #pragma unroll
        for (int n2 = 0; n2 < 8; ++n2)
            #pragma unroll
            for (int c = 0; c < 2; ++c) {
                bf16x8 bv = *(const bf16x8*)(Vs + (size_t)(n2 * 16 + cl) * 64 + (((c * 4 + quad) ^ (cl & 7)) << 3));
                oacc[n2] = __builtin_amdgcn_mfma_f32_16x16x32_bf16(ap[c], bv, oacc[n2], 0, 0, 0);
            }
    }

    // epilogue: reduce l across the 16 col-lanes once, O/l, sigmoid gate, store
    #pragma unroll
    for (int r = 0; r < 4; ++r) {
        #pragma unroll
        for (int off = 8; off; off >>= 1) lstate[r] += __shfl_xor(lstate[r], off);
        int srow = qt * 128 + wave * 16 + quad * 4 + r;
        float linv = 1.0f / lstate[r];
        #pragma unroll
        for (int n2 = 0; n2 < 8; ++n2) {
            int d = n2 * 16 + cl;
            float g = (float)qkv[(size_t)(b * SEQ + srow) * NQKV + head * 256 + 128 + d];
            float sig = 1.0f / (1.0f + __expf(-g));
            float v = oacc[n2][r] * linv * sig;
            attnb[(size_t)(b * SEQ + srow) * HID + head * HD + d] = (bf16)v;
        }
    }
}

// ---------------- launch ----------------
extern "C" void kernel_launch(void* const* d_in, const int* in_sizes, int n_in,
                              void* d_out, int out_size, void* d_ws, size_t ws_size,
                              hipStream_t stream) {
    const float* x        = (const float*)d_in[0];
    const int*   amask    = (const int*)d_in[1];
    const int*   positions= (const int*)d_in[2];
    const float* Wq       = (const float*)d_in[3];
    const float* Wk       = (const float*)d_in[4];
    const float* Wv       = (const float*)d_in[5];
    const float* Wo       = (const float*)d_in[6];
    const float* qnw      = (const float*)d_in[7];
    const float* knw      = (const float*)d_in[8];
    float* out = (float*)d_out;
    char* ws = (char*)d_ws;

    bf16* xb    = (bf16*)(ws);                         // 16,777,216 B
    bf16* wqkvT = (bf16*)(ws + 16777216);              // 25,165,824 B
    bf16* woT   = (bf16*)(ws + 41943040);              //  8,388,608 B
    bf16* qkv   = (bf16*)(ws + 50331648);              // 50,331,648 B
    bf16* Qh    = (bf16*)(ws + 100663296);             // 16,777,216 B
    bf16* Kh    = (bf16*)(ws + 117440512);             //  8,388,608 B
    bf16* VT    = (bf16*)(ws + 125829120);             //  8,388,608 B
    bf16* attnb = (bf16*)(ws + 134217728);             // 16,777,216 B -> 150,994,944 total

    prep_kernel<<<12288, 256, 0, stream>>>(x, xb, Wq, Wk, Wv, Wo, wqkvT, woT);
    gemm_bt<true><<<dim3(48, 32), 256, 0, stream>>>(xb, wqkvT, qkv, MTOT, NQKV, HID);
    post_kernel<<<4608, 256, 0, stream>>>(qkv, qnw, knw, positions, Qh, Kh, VT);
    attn_kernel<<<512, 512, 0, stream>>>(Qh, Kh, VT, qkv, amask, attnb);
    gemm_bt<false><<<dim3(16, 32), 256, 0, stream>>>(attnb, woT, out, MTOT, HID, HID);

    (void)in_sizes; (void)n_in; (void)out_size; (void)ws_size;
}